// Round 6
// baseline (464.681 us; speedup 1.0000x reference)
//
#include <hip/hip_runtime.h>
#include <hip/hip_bf16.h>

// MPNN: B=8, N=36, H=64, STEPS=5
// messages[b,j,k] = (1/N^2) * sum_{i,l} edge[b,i,j,k,l] * nodes[b,i,l]
// nodes = GRUCell(messages, nodes) * mask, repeated STEPS times.
//
// Structure (6 launches):
//  L1: einsum(f32 edge, nodes0) -> partialA, + emit bf16 edge copy (85 MB)
//  L2..L5: fused kernel: GRU prologue recomputes nodes_{s-1} per block from
//          partial_prev + nodes_{s-2} (redundant across j, identical values),
//          then einsum over the bf16 copy -> partial_cur
//  L6: final GRU -> d_out

#define BB 8
#define NN 36
#define HH 64
#define GG 12           // i-groups per (b,j) for the einsum split
#define IPG (NN / GG)   // 3 i per group
#define NSTEPS 5
#define INVN2 (1.0f / (float)(NN * NN))

__device__ __forceinline__ unsigned bf16rtn(float f) {
    unsigned u = __float_as_uint(f);
    return (u + 0x7FFFu + ((u >> 16) & 1u)) >> 16;
}

// Per-lane GRU cell: lane t computes output dim t of node stored in
// ms[64] (message) / hs[64] (hidden), using LDS-staged vectors.
__device__ __forceinline__ float gru_lane(
    const float* __restrict__ ms, const float* __restrict__ hs, int t,
    const float* __restrict__ w_ih, const float* __restrict__ w_hh,
    const float* __restrict__ b_ih, const float* __restrict__ b_hh)
{
    float gi0 = b_ih[t], gi1 = b_ih[HH + t], gi2 = b_ih[2 * HH + t];
    float gh0 = b_hh[t], gh1 = b_hh[HH + t], gh2 = b_hh[2 * HH + t];

    const float4* __restrict__ wi0 = (const float4*)(w_ih + (0 * HH + t) * HH);
    const float4* __restrict__ wi1 = (const float4*)(w_ih + (1 * HH + t) * HH);
    const float4* __restrict__ wi2 = (const float4*)(w_ih + (2 * HH + t) * HH);
    const float4* __restrict__ wh0 = (const float4*)(w_hh + (0 * HH + t) * HH);
    const float4* __restrict__ wh1 = (const float4*)(w_hh + (1 * HH + t) * HH);
    const float4* __restrict__ wh2 = (const float4*)(w_hh + (2 * HH + t) * HH);

    #pragma unroll
    for (int k4 = 0; k4 < HH / 4; ++k4) {
        const float4 mv = *(const float4*)&ms[k4 * 4];
        const float4 hv = *(const float4*)&hs[k4 * 4];
        float4 a;
        a = wi0[k4]; gi0 += a.x * mv.x + a.y * mv.y + a.z * mv.z + a.w * mv.w;
        a = wi1[k4]; gi1 += a.x * mv.x + a.y * mv.y + a.z * mv.z + a.w * mv.w;
        a = wi2[k4]; gi2 += a.x * mv.x + a.y * mv.y + a.z * mv.z + a.w * mv.w;
        a = wh0[k4]; gh0 += a.x * hv.x + a.y * hv.y + a.z * hv.z + a.w * hv.w;
        a = wh1[k4]; gh1 += a.x * hv.x + a.y * hv.y + a.z * hv.z + a.w * hv.w;
        a = wh2[k4]; gh2 += a.x * hv.x + a.y * hv.y + a.z * hv.z + a.w * hv.w;
    }
    const float r = 1.f / (1.f + expf(-(gi0 + gh0)));
    const float z = 1.f / (1.f + expf(-(gi1 + gh1)));
    const float n = tanhf(gi2 + r * gh2);
    return (1.f - z) * n + z * hs[t];
}

// ---------------------------------------------------------------------------
// L1: partial einsum on f32 edge + emit bf16 edge copy.
// grid = BB*NN*GG blocks of 64. bid = (b*NN + j)*GG + g. Lane reads float4
// chunk it*64+lane (coalesced 1KB/instr); k = 4*it + lane/16, l4 = lane%16.
// acc[16] static; 4-stage butterfly over low 4 lane bits; lane (p,gq)
// writes k = 4*p+gq. Each float4 also converted RTN->bf16, stored as uint2.
// ---------------------------------------------------------------------------
__global__ __launch_bounds__(64) void einsum_f32_cvt(
    const float* __restrict__ edge,
    const float* __restrict__ nodes,
    float* __restrict__ partial,
    uint2* __restrict__ ebf)
{
    const int lane = threadIdx.x;
    const int bid  = blockIdx.x;
    const int g = bid % GG;
    const int j = (bid / GG) % NN;
    const int b = bid / (GG * NN);

    const int l4 = lane & 15;

    float acc[16];
    #pragma unroll
    for (int it = 0; it < 16; ++it) acc[it] = 0.f;

    #pragma unroll
    for (int ii = 0; ii < IPG; ++ii) {
        const int i = g * IPG + ii;
        const float4 v = *(const float4*)(nodes + (b * NN + i) * HH + l4 * 4);
        const size_t blkElem = (size_t)((b * NN + i) * NN + j) * (HH * HH);
        const float4* __restrict__ Wb = (const float4*)(edge + blkElem);
        uint2* __restrict__ Eb = ebf + (blkElem >> 2);
        #pragma unroll
        for (int it = 0; it < 16; ++it) {
            const float4 w = Wb[it * 64 + lane];
            acc[it] = fmaf(w.x, v.x, acc[it]);
            acc[it] = fmaf(w.y, v.y, acc[it]);
            acc[it] = fmaf(w.z, v.z, acc[it]);
            acc[it] = fmaf(w.w, v.w, acc[it]);
            uint2 pk;
            pk.x = bf16rtn(w.x) | (bf16rtn(w.y) << 16);
            pk.y = bf16rtn(w.z) | (bf16rtn(w.w) << 16);
            Eb[it * 64 + lane] = pk;
        }
    }

    #pragma unroll
    for (int m = 1; m < 16; m <<= 1) {
        #pragma unroll
        for (int it = 0; it < 16; ++it)
            acc[it] += __shfl_xor(acc[it], m, 64);
    }

    const int p  = lane & 15;
    const int gq = lane >> 4;
    float outv = acc[0];
    #pragma unroll
    for (int t = 1; t < 16; ++t) outv = (p == t) ? acc[t] : outv;

    partial[(size_t)bid * HH + (4 * p + gq)] = outv;
}

// ---------------------------------------------------------------------------
// L2..L5: GRU prologue (recompute nodes_{s-1} for this block's 3 i-nodes,
// redundantly across the 36 j-blocks) + einsum on the bf16 edge copy.
// ---------------------------------------------------------------------------
__global__ __launch_bounds__(64) void einsum_bf16_fused(
    const uint4* __restrict__ ebf,
    const float* __restrict__ partial_prev,   // messages for step s-1 (pre-sum)
    const float* __restrict__ nodes_pp,       // nodes_{s-2} (hidden state h)
    const float* __restrict__ mask,
    const float* __restrict__ w_ih,
    const float* __restrict__ w_hh,
    const float* __restrict__ b_ih,
    const float* __restrict__ b_hh,
    float* __restrict__ nodes_out,            // nodes_{s-1} (redundant write)
    float* __restrict__ partial_out)
{
    const int lane = threadIdx.x;
    const int bid  = blockIdx.x;
    const int g = bid % GG;
    const int j = (bid / GG) % NN;
    const int b = bid / (GG * NN);
    const int t = lane;

    __shared__ float ms[IPG][HH];
    __shared__ float hs[IPG][HH];
    __shared__ float nd[IPG][HH];

    // --- GRU prologue: nodes_{s-1}[b, i in group] ---
    #pragma unroll
    for (int ii = 0; ii < IPG; ++ii) {
        const int i = g * IPG + ii;
        float m = 0.f;
        #pragma unroll
        for (int gp = 0; gp < GG; ++gp)
            m += partial_prev[((size_t)(b * NN + i) * GG + gp) * HH + t];
        ms[ii][t] = m * INVN2;
        hs[ii][t] = nodes_pp[(b * NN + i) * HH + t];
    }
    __syncthreads();

    #pragma unroll
    for (int ii = 0; ii < IPG; ++ii) {
        const int i = g * IPG + ii;
        float outv = gru_lane(ms[ii], hs[ii], t, w_ih, w_hh, b_ih, b_hh);
        outv *= mask[b * NN + i];
        nd[ii][t] = outv;
        nodes_out[(b * NN + i) * HH + t] = outv;   // identical across j-blocks
    }
    __syncthreads();

    // --- einsum over bf16 edge copy, nodes from LDS ---
    const int l8 = lane & 7;

    float acc[8];
    #pragma unroll
    for (int it = 0; it < 8; ++it) acc[it] = 0.f;

    #pragma unroll
    for (int ii = 0; ii < IPG; ++ii) {
        const int i = g * IPG + ii;
        const float4 v0 = *(const float4*)&nd[ii][l8 * 8];
        const float4 v1 = *(const float4*)&nd[ii][l8 * 8 + 4];
        const size_t blkElem = (size_t)((b * NN + i) * NN + j) * (HH * HH);
        const uint4* __restrict__ Wb = ebf + (blkElem >> 3);
        #pragma unroll
        for (int it = 0; it < 8; ++it) {
            const uint4 w = Wb[it * 64 + lane];
            acc[it] = fmaf(__uint_as_float(w.x << 16),          v0.x, acc[it]);
            acc[it] = fmaf(__uint_as_float(w.x & 0xffff0000u),  v0.y, acc[it]);
            acc[it] = fmaf(__uint_as_float(w.y << 16),          v0.z, acc[it]);
            acc[it] = fmaf(__uint_as_float(w.y & 0xffff0000u),  v0.w, acc[it]);
            acc[it] = fmaf(__uint_as_float(w.z << 16),          v1.x, acc[it]);
            acc[it] = fmaf(__uint_as_float(w.z & 0xffff0000u),  v1.y, acc[it]);
            acc[it] = fmaf(__uint_as_float(w.w << 16),          v1.z, acc[it]);
            acc[it] = fmaf(__uint_as_float(w.w & 0xffff0000u),  v1.w, acc[it]);
        }
    }

    #pragma unroll
    for (int m = 1; m < 8; m <<= 1) {
        #pragma unroll
        for (int it = 0; it < 8; ++it)
            acc[it] += __shfl_xor(acc[it], m, 64);
    }

    const int p  = lane & 7;
    const int gq = lane >> 3;
    float outv = acc[0];
    #pragma unroll
    for (int tt = 1; tt < 8; ++tt) outv = (p == tt) ? acc[tt] : outv;

    partial_out[(size_t)bid * HH + (8 * p + gq)] = outv;
}

// ---------------------------------------------------------------------------
// L6: final GRU -> d_out. grid = BB*NN blocks of 64.
// ---------------------------------------------------------------------------
__global__ __launch_bounds__(64) void gru_final(
    const float* __restrict__ partial,
    const float* __restrict__ nodes_in,
    const float* __restrict__ mask,
    const float* __restrict__ w_ih,
    const float* __restrict__ w_hh,
    const float* __restrict__ b_ih,
    const float* __restrict__ b_hh,
    float* __restrict__ nodes_out)
{
    const int t  = threadIdx.x;
    const int bj = blockIdx.x;

    float m = 0.f;
    #pragma unroll
    for (int g = 0; g < GG; ++g)
        m += partial[((size_t)bj * GG + g) * HH + t];

    __shared__ float ms[HH];
    __shared__ float hs[HH];
    ms[t] = m * INVN2;
    hs[t] = nodes_in[bj * HH + t];
    __syncthreads();

    float outv = gru_lane(ms, hs, t, w_ih, w_hh, b_ih, b_hh);
    outv *= mask[bj];
    nodes_out[bj * HH + t] = outv;
}

extern "C" void kernel_launch(void* const* d_in, const int* in_sizes, int n_in,
                              void* d_out, int out_size, void* d_ws, size_t ws_size,
                              hipStream_t stream) {
    const float* edge   = (const float*)d_in[0];
    const float* nodes0 = (const float*)d_in[1];
    const float* mask   = (const float*)d_in[2];
    const float* w_ih   = (const float*)d_in[3];
    const float* w_hh   = (const float*)d_in[4];
    const float* b_ih   = (const float*)d_in[5];
    const float* b_hh   = (const float*)d_in[6];
    float* out = (float*)d_out;

    float* ws = (float*)d_ws;
    const int nodes_elems   = BB * NN * HH;                // 18432
    const int partial_elems = BB * NN * GG * HH;           // 221184
    float* nodesA   = ws;
    float* nodesB   = ws + nodes_elems;
    float* partialA = ws + 2 * nodes_elems;
    float* partialB = partialA + partial_elems;
    float* ebf_f    = partialB + partial_elems;            // bf16 edge copy ~88.5 MB
    uint2* ebf2 = (uint2*)ebf_f;
    const uint4* ebf4 = (const uint4*)ebf_f;

    const int grid_e = BB * NN * GG;   // 3456

    // L1: messages1 -> partialA (+ bf16 edge copy)
    einsum_f32_cvt<<<grid_e, 64, 0, stream>>>(edge, nodes0, partialA, ebf2);

    // L2: nodes1 = GRU(partialA, nodes0); messages2 -> partialB
    einsum_bf16_fused<<<grid_e, 64, 0, stream>>>(ebf4, partialA, nodes0, mask,
                                                 w_ih, w_hh, b_ih, b_hh,
                                                 nodesA, partialB);
    // L3: nodes2 = GRU(partialB, nodes1); messages3 -> partialA
    einsum_bf16_fused<<<grid_e, 64, 0, stream>>>(ebf4, partialB, nodesA, mask,
                                                 w_ih, w_hh, b_ih, b_hh,
                                                 nodesB, partialA);
    // L4: nodes3 = GRU(partialA, nodes2); messages4 -> partialB
    einsum_bf16_fused<<<grid_e, 64, 0, stream>>>(ebf4, partialA, nodesB, mask,
                                                 w_ih, w_hh, b_ih, b_hh,
                                                 nodesA, partialB);
    // L5: nodes4 = GRU(partialB, nodes3); messages5 -> partialA
    einsum_bf16_fused<<<grid_e, 64, 0, stream>>>(ebf4, partialB, nodesA, mask,
                                                 w_ih, w_hh, b_ih, b_hh,
                                                 nodesB, partialA);
    // L6: out = GRU(partialA, nodes4)
    gru_final<<<BB * NN, 64, 0, stream>>>(partialA, nodesB, mask,
                                          w_ih, w_hh, b_ih, b_hh, out);
}